// Round 1
// baseline (1323.443 us; speedup 1.0000x reference)
//
#include <hip/hip_runtime.h>
#include <hip/hip_bf16.h>
#include <stdint.h>

// Problem: out[k,b,d] = sum_{i} s(k,i) * (x[i*B:(i+1)*B] @ W[:, j(k,i)*D:(j(k,i)+1)*D])[b,d] + bias[k*D+d]
// where (j,s) come from the (3,0,0) Clifford blade product: blade_i * blade_j = s * blade_k.
// B=2048, DIN=2048, D=2048, 8 blades. 1.10 TFLOP total.

#define MB 8
#define BATCH 2048
#define DIN 2048
#define DD 2048
#define NR (MB * BATCH)  // 16384 rows of x
#define UU (MB * DD)     // 16384 cols of W

#define BM 128
#define BN 128
#define BK 64

typedef __attribute__((ext_vector_type(8))) __bf16 bf16x8;
typedef __attribute__((ext_vector_type(4))) float f32x4;
typedef __attribute__((ext_vector_type(4))) unsigned int u32x4;

// j(k,i): blade index such that blade_i * blade_j = s * blade_k  (j = mask(i)^mask(k))
__constant__ int c_jmap[8][8] = {
    {0, 1, 2, 3, 4, 5, 6, 7},
    {1, 0, 4, 5, 2, 3, 7, 6},
    {2, 4, 0, 6, 1, 7, 3, 5},
    {3, 5, 6, 0, 7, 1, 2, 4},
    {4, 2, 1, 7, 0, 6, 5, 3},
    {5, 3, 7, 1, 6, 0, 4, 2},
    {6, 7, 3, 2, 5, 4, 0, 1},
    {7, 6, 5, 4, 3, 2, 1, 0}};
// sign as bf16x2 xor mask (0x80008000 = negate both halves)
#define NEG 0x80008000u
__constant__ unsigned int c_smask[8][8] = {
    {0, 0, 0, 0, NEG, NEG, NEG, NEG},
    {0, 0, NEG, NEG, 0, 0, NEG, NEG},
    {0, 0, 0, NEG, NEG, 0, 0, 0},
    {0, 0, 0, 0, NEG, NEG, NEG, NEG},
    {0, 0, NEG, 0, 0, NEG, 0, 0},
    {0, 0, NEG, NEG, 0, 0, NEG, NEG},
    {0, 0, 0, NEG, NEG, 0, 0, 0},
    {0, 0, NEG, 0, 0, NEG, 0, 0}};

__device__ __forceinline__ unsigned short f2bf(float f) {
  unsigned int u = __float_as_uint(f);
  u = (u + 0x7FFFu + ((u >> 16) & 1u)) >> 16;  // RNE
  return (unsigned short)u;
}

__global__ void cast_x_kernel(const float* __restrict__ x,
                              unsigned short* __restrict__ o, int n4) {
  int i = blockIdx.x * blockDim.x + threadIdx.x;
  if (i >= n4) return;
  float4 v = ((const float4*)x)[i];
  ushort4 r;
  r.x = f2bf(v.x);
  r.y = f2bf(v.y);
  r.z = f2bf(v.z);
  r.w = f2bf(v.w);
  ((ushort4*)o)[i] = r;
}

// W [DIN][UU] fp32 -> Wt [UU][DIN] bf16 (so GEMM B-fragments are k-contiguous)
__global__ void transpose_cast_w(const float* __restrict__ W,
                                 unsigned short* __restrict__ Wt) {
  __shared__ float tile[32][33];
  int x = threadIdx.x & 31;
  int y = threadIdx.x >> 5;  // 0..7
  int c0 = blockIdx.x * 32;  // col block in W
  int r0 = blockIdx.y * 32;  // row block in W
#pragma unroll
  for (int j = 0; j < 32; j += 8)
    tile[y + j][x] = W[(size_t)(r0 + y + j) * UU + (c0 + x)];
  __syncthreads();
#pragma unroll
  for (int j = 0; j < 32; j += 8)
    Wt[(size_t)(c0 + y + j) * DIN + (r0 + x)] = f2bf(tile[x][y + j]);
}

__device__ __forceinline__ void gl_lds16(const void* g, void* l) {
  __builtin_amdgcn_global_load_lds((__attribute__((address_space(1))) void*)g,
                                   (__attribute__((address_space(3))) void*)l,
                                   16, 0, 0);
}

union FragU {
  u32x4 u;
  bf16x8 v;
};

// grid (DD/BN, BATCH/BM, 8); block 256 (4 waves, 2x2, each wave 64x64 out)
__global__ __launch_bounds__(256) void ga_gemm(
    const unsigned short* __restrict__ Xb,   // [NR][DIN] bf16
    const unsigned short* __restrict__ Wt,   // [UU][DIN] bf16 (= W^T)
    const float* __restrict__ bias,          // [UU]
    float* __restrict__ out) {               // [NR][DD] fp32
  __shared__ u32x4 ldsA[BM * BK / 8];  // 1024 x 16B = 16 KB
  __shared__ u32x4 ldsB[BN * BK / 8];

  const int tid = threadIdx.x;
  const int kb = blockIdx.z;
  const int tm = blockIdx.y;
  const int tn = blockIdx.x;
  const int wid = tid >> 6;
  const int lane = tid & 63;
  const int wr = wid & 1;
  const int wc = wid >> 1;
  const int lrow = lane & 15;
  const int q = lane >> 4;
  const int l7 = lane & 7;

  f32x4 acc[4][4] = {};

  // Staging: LDS chunk L holds global 16B chunk (m = L>>3, c = (L&7) ^ (m&7)).
  // XOR swizzle makes fragment ds_read_b128 2-way-bank-aliased only (free).
  int smM[4], smC[4];
#pragma unroll
  for (int t = 0; t < 4; ++t) {
    int L = wid * 256 + t * 64 + lane;
    smM[t] = L >> 3;
    smC[t] = (L & 7) ^ ((L >> 3) & 7);
  }

  for (int iseg = 0; iseg < MB; ++iseg) {
    const size_t arow0 = (size_t)(iseg * BATCH + tm * BM);
    const size_t brow0 = (size_t)(c_jmap[kb][iseg] * DD + tn * BN);
    const unsigned int smask = c_smask[kb][iseg];

    for (int k0 = 0; k0 < DIN; k0 += BK) {
#pragma unroll
      for (int t = 0; t < 4; ++t) {
        const unsigned short* ga = Xb + (arow0 + smM[t]) * DIN + (k0 + smC[t] * 8);
        gl_lds16(ga, &ldsA[wid * 256 + t * 64]);  // HW: uniform base + lane*16
        const unsigned short* gb = Wt + (brow0 + smM[t]) * DIN + (k0 + smC[t] * 8);
        gl_lds16(gb, &ldsB[wid * 256 + t * 64]);
      }
      __syncthreads();  // compiler drains vmcnt before s_barrier

#pragma unroll
      for (int kk = 0; kk < 2; ++kk) {
        FragU af[4], bf[4];
        const int p = (kk * 4 + q) ^ l7;
#pragma unroll
        for (int mt = 0; mt < 4; ++mt) {
          int m_local = wr * 64 + mt * 16 + lrow;
          af[mt].u = ldsA[m_local * 8 + p];
        }
        if (smask) {  // block-uniform branch: negate A fragments
#pragma unroll
          for (int mt = 0; mt < 4; ++mt) af[mt].u ^= smask;
        }
#pragma unroll
        for (int nt = 0; nt < 4; ++nt) {
          int n_local = wc * 64 + nt * 16 + lrow;
          bf[nt].u = ldsB[n_local * 8 + p];
        }
#pragma unroll
        for (int mt = 0; mt < 4; ++mt)
#pragma unroll
          for (int nt = 0; nt < 4; ++nt)
            acc[mt][nt] = __builtin_amdgcn_mfma_f32_16x16x32_bf16(
                af[mt].v, bf[nt].v, acc[mt][nt], 0, 0, 0);
      }
      __syncthreads();
    }
  }

  // Epilogue: C/D layout col = lane&15, row = q*4 + reg (m89-verified)
#pragma unroll
  for (int nt = 0; nt < 4; ++nt) {
    const int col = tn * BN + wc * 64 + nt * 16 + lrow;
    const float bv = bias[kb * DD + col];
#pragma unroll
    for (int mt = 0; mt < 4; ++mt) {
      const int row = tm * BM + wr * 64 + mt * 16 + q * 4;
#pragma unroll
      for (int r = 0; r < 4; ++r) {
        out[((size_t)(kb * BATCH + row + r)) * DD + col] = acc[mt][nt][r] + bv;
      }
    }
  }
}

extern "C" void kernel_launch(void* const* d_in, const int* in_sizes, int n_in,
                              void* d_out, int out_size, void* d_ws,
                              size_t ws_size, hipStream_t stream) {
  const float* x = (const float*)d_in[0];     // [16384][2048]
  const float* W = (const float*)d_in[1];     // [2048][16384]
  const float* bias = (const float*)d_in[2];  // [16384]
  float* out = (float*)d_out;                 // [16384][2048]

  // workspace layout: xb (67 MB bf16) | wt (67 MB bf16) -> needs 128 MiB
  unsigned short* xb = (unsigned short*)d_ws;
  unsigned short* wt = xb + (size_t)NR * DIN;

  int n4 = (NR * DIN) / 4;  // 8388608
  cast_x_kernel<<<n4 / 256, 256, 0, stream>>>(x, xb, n4);

  dim3 tg(UU / 32, DIN / 32);  // (512, 64)
  transpose_cast_w<<<tg, 256, 0, stream>>>(W, wt);

  dim3 gg(DD / BN, BATCH / BM, MB);  // (16, 16, 8)
  ga_gemm<<<gg, 256, 0, stream>>>(xb, wt, bias, out);
}

// Round 2
// 1192.862 us; speedup vs baseline: 1.1095x; 1.1095x over previous
//
#include <hip/hip_runtime.h>
#include <hip/hip_bf16.h>
#include <stdint.h>

// R2: wave tile 64x64 -> 128x64 (BM=256,BN=128): LDS frag traffic 1/32 -> 1/42.7 B/FLOP
//     (64x64 tile needs 74 TB/s LDS at full MFMA rate — above the 69 TB/s ceiling).
//     Prologue rewritten: 64x64 transpose tiles, float4 in / ushort8 out; cast_x 16B stores.
// out[k,b,d] = sum_i s(k,i) * (x_i @ W[:, j(k,i)]) + bias; (3,0,0) Clifford. 1.10 TFLOP.

#define MB 8
#define BATCH 2048
#define DIN 2048
#define DD 2048
#define NR (MB * BATCH)
#define UU (MB * DD)

#define BM 256
#define BN 128
#define BK 64

typedef __attribute__((ext_vector_type(8))) __bf16 bf16x8;
typedef __attribute__((ext_vector_type(4))) float f32x4;
typedef __attribute__((ext_vector_type(4))) unsigned int u32x4;

__constant__ int c_jmap[8][8] = {
    {0, 1, 2, 3, 4, 5, 6, 7},
    {1, 0, 4, 5, 2, 3, 7, 6},
    {2, 4, 0, 6, 1, 7, 3, 5},
    {3, 5, 6, 0, 7, 1, 2, 4},
    {4, 2, 1, 7, 0, 6, 5, 3},
    {5, 3, 7, 1, 6, 0, 4, 2},
    {6, 7, 3, 2, 5, 4, 0, 1},
    {7, 6, 5, 4, 3, 2, 1, 0}};
#define NEG 0x80008000u
__constant__ unsigned int c_smask[8][8] = {
    {0, 0, 0, 0, NEG, NEG, NEG, NEG},
    {0, 0, NEG, NEG, 0, 0, NEG, NEG},
    {0, 0, 0, NEG, NEG, 0, 0, 0},
    {0, 0, 0, 0, NEG, NEG, NEG, NEG},
    {0, 0, NEG, 0, 0, NEG, 0, 0},
    {0, 0, NEG, NEG, 0, 0, NEG, NEG},
    {0, 0, 0, NEG, NEG, 0, 0, 0},
    {0, 0, NEG, 0, 0, NEG, 0, 0}};

__device__ __forceinline__ unsigned short f2bf(float f) {
  unsigned int u = __float_as_uint(f);
  u = (u + 0x7FFFu + ((u >> 16) & 1u)) >> 16;  // RNE
  return (unsigned short)u;
}

// x fp32 -> bf16, 8 elems/thread (32B in, 16B out)
__global__ void cast_x_kernel(const float* __restrict__ x,
                              unsigned short* __restrict__ o, int n8) {
  int i = blockIdx.x * blockDim.x + threadIdx.x;
  if (i >= n8) return;
  float4 a = ((const float4*)x)[i * 2];
  float4 b = ((const float4*)x)[i * 2 + 1];
  ushort s[8] = {f2bf(a.x), f2bf(a.y), f2bf(a.z), f2bf(a.w),
                 f2bf(b.x), f2bf(b.y), f2bf(b.z), f2bf(b.w)};
  u32x4 p;
  p[0] = (unsigned)s[0] | ((unsigned)s[1] << 16);
  p[1] = (unsigned)s[2] | ((unsigned)s[3] << 16);
  p[2] = (unsigned)s[4] | ((unsigned)s[5] << 16);
  p[3] = (unsigned)s[6] | ((unsigned)s[7] << 16);
  ((u32x4*)o)[i] = p;
}

// W [DIN][UU] fp32 -> Wt [UU][DIN] bf16. 64x64 tiles, 256 threads.
__global__ void transpose_cast_w(const float* __restrict__ W,
                                 unsigned short* __restrict__ Wt) {
  __shared__ float tile[64][65];
  const int tid = threadIdx.x;
  const int c0 = blockIdx.x * 64;  // col block in W (row block in Wt)
  const int r0 = blockIdx.y * 64;  // row block in W (k)
  {
    const int row = tid >> 4;         // 0..15 (+16j)
    const int col = (tid & 15) * 4;   // 0..60
#pragma unroll
    for (int j = 0; j < 4; ++j) {
      float4 v = *(const float4*)&W[(size_t)(r0 + row + j * 16) * UU + c0 + col];
      tile[row + j * 16][col + 0] = v.x;
      tile[row + j * 16][col + 1] = v.y;
      tile[row + j * 16][col + 2] = v.z;
      tile[row + j * 16][col + 3] = v.w;
    }
  }
  __syncthreads();
  {
    const int rc = (tid & 7) * 8;  // r-chunk of 8
    int c = tid >> 3;              // 0..31, then +32
#pragma unroll
    for (int h = 0; h < 2; ++h, c += 32) {
      u32x4 p;
#pragma unroll
      for (int w = 0; w < 4; ++w) {
        unsigned lo = f2bf(tile[rc + w * 2][c]);
        unsigned hi = f2bf(tile[rc + w * 2 + 1][c]);
        p[w] = lo | (hi << 16);
      }
      *(u32x4*)&Wt[(size_t)(c0 + c) * DIN + r0 + rc] = p;
    }
  }
}

__device__ __forceinline__ void gl_lds16(const void* g, void* l) {
  __builtin_amdgcn_global_load_lds((__attribute__((address_space(1))) void*)g,
                                   (__attribute__((address_space(3))) void*)l,
                                   16, 0, 0);
}

union FragU {
  u32x4 u;
  bf16x8 v;
};

// grid (DD/BN=16, BATCH/BM=8, 8); block 256 = 4 waves (2x2), wave tile 128x64.
__global__ __launch_bounds__(256, 2) void ga_gemm(
    const unsigned short* __restrict__ Xb,   // [NR][DIN] bf16
    const unsigned short* __restrict__ Wt,   // [UU][DIN] bf16 (= W^T)
    const float* __restrict__ bias,          // [UU]
    float* __restrict__ out) {               // [NR][DD] fp32
  __shared__ u32x4 ldsA[BM * BK / 8];  // 2048 chunks = 32 KB
  __shared__ u32x4 ldsB[BN * BK / 8];  // 1024 chunks = 16 KB

  const int tid = threadIdx.x;
  const int kb = blockIdx.z;
  const int tm = blockIdx.y;
  const int tn = blockIdx.x;
  const int wid = tid >> 6;
  const int lane = tid & 63;
  const int wr = wid & 1;   // wave row: 0/1 -> 128-row half
  const int wc = wid >> 1;  // wave col: 0/1 -> 64-col half
  const int lrow = lane & 15;
  const int q = lane >> 4;
  const int l7 = lane & 7;

  f32x4 acc[8][4] = {};

  for (int iseg = 0; iseg < MB; ++iseg) {
    const size_t arow0 = (size_t)(iseg * BATCH + tm * BM);
    const size_t brow0 = (size_t)(c_jmap[kb][iseg] * DD + tn * BN);
    const unsigned int smask = c_smask[kb][iseg];

    for (int k0 = 0; k0 < DIN; k0 += BK) {
      // Stage A: 2048 chunks, 8 insts/thread; XOR swizzle on the GLOBAL source
      // address (slot L holds logical chunk (L&7)^((L>>3)&7) of row L>>3) so
      // LDS stays lane-contiguous for global_load_lds.
#pragma unroll
      for (int t = 0; t < 8; ++t) {
        const int L = (t * 4 + wid) * 64 + lane;
        const int m = L >> 3;
        const int c = (L & 7) ^ (m & 7);
        gl_lds16(Xb + (arow0 + m) * DIN + (k0 + c * 8),
                 &ldsA[(t * 4 + wid) * 64]);
      }
#pragma unroll
      for (int t = 0; t < 4; ++t) {
        const int L = (t * 4 + wid) * 64 + lane;
        const int m = L >> 3;
        const int c = (L & 7) ^ (m & 7);
        gl_lds16(Wt + (brow0 + m) * DIN + (k0 + c * 8),
                 &ldsB[(t * 4 + wid) * 64]);
      }
      __syncthreads();

#pragma unroll
      for (int kk = 0; kk < 2; ++kk) {
        FragU af[8], bf[4];
        const int p = (kk * 4 + q) ^ l7;
#pragma unroll
        for (int mt = 0; mt < 8; ++mt) {
          const int m_local = wr * 128 + mt * 16 + lrow;
          af[mt].u = ldsA[m_local * 8 + p];
        }
        if (smask) {  // block-uniform: negate A fragments
#pragma unroll
          for (int mt = 0; mt < 8; ++mt) af[mt].u ^= smask;
        }
#pragma unroll
        for (int nt = 0; nt < 4; ++nt) {
          const int n_local = wc * 64 + nt * 16 + lrow;
          bf[nt].u = ldsB[n_local * 8 + p];
        }
#pragma unroll
        for (int mt = 0; mt < 8; ++mt)
#pragma unroll
          for (int nt = 0; nt < 4; ++nt)
            acc[mt][nt] = __builtin_amdgcn_mfma_f32_16x16x32_bf16(
                af[mt].v, bf[nt].v, acc[mt][nt], 0, 0, 0);
      }
      __syncthreads();
    }
  }

  // C/D layout: col = lane&15, row = q*4 + reg (m89-verified)
#pragma unroll
  for (int nt = 0; nt < 4; ++nt) {
    const int col = tn * BN + wc * 64 + nt * 16 + lrow;
    const float bv = bias[kb * DD + col];
#pragma unroll
    for (int mt = 0; mt < 8; ++mt) {
      const int row = tm * BM + wr * 128 + mt * 16 + q * 4;
#pragma unroll
      for (int r = 0; r < 4; ++r) {
        out[((size_t)(kb * BATCH + row + r)) * DD + col] = acc[mt][nt][r] + bv;
      }
    }
  }
}

extern "C" void kernel_launch(void* const* d_in, const int* in_sizes, int n_in,
                              void* d_out, int out_size, void* d_ws,
                              size_t ws_size, hipStream_t stream) {
  const float* x = (const float*)d_in[0];     // [16384][2048]
  const float* W = (const float*)d_in[1];     // [2048][16384]
  const float* bias = (const float*)d_in[2];  // [16384]
  float* out = (float*)d_out;                 // [16384][2048]

  unsigned short* xb = (unsigned short*)d_ws;          // 67 MB bf16
  unsigned short* wt = xb + (size_t)NR * DIN;          // 67 MB bf16

  int n8 = (NR * DIN) / 8;  // 4194304
  cast_x_kernel<<<n8 / 256, 256, 0, stream>>>(x, xb, n8);

  dim3 tg(UU / 64, DIN / 64);  // (256, 32)
  transpose_cast_w<<<tg, 256, 0, stream>>>(W, wt);

  dim3 gg(DD / BN, BATCH / BM, MB);  // (16, 8, 8) = 1024 blocks
  ga_gemm<<<gg, 256, 0, stream>>>(xb, wt, bias, out);
}